// Round 1
// baseline (2762.964 us; speedup 1.0000x reference)
//
#include <hip/hip_runtime.h>

#define NT 64
#define NH 12
#define HD 32
#define DIM 384
#define NWIN 4096
#define TPB 512
#define PTPB 256

typedef __bf16 bf16;
typedef __bf16 bf16x8 __attribute__((ext_vector_type(8)));
typedef float floatx4 __attribute__((ext_vector_type(4)));

// bf16 weights + fully-expanded rel-pos bias (rewritten every launch; idempotent).
__device__ __align__(16) bf16 g_wqkv[3 * DIM * DIM];   // [1152][384] row = out-channel
__device__ __align__(16) bf16 g_wproj[DIM * DIM];      // [384][384]  row = out-channel
__device__ __align__(16) float g_biasF[NH * NT * NT];  // [12][64][64] bias[h][q][kv]

__global__ void convert_weights(const float* __restrict__ qkv_w,
                                const float* __restrict__ proj_w,
                                const float* __restrict__ bias_table) {
    int i = blockIdx.x * blockDim.x + threadIdx.x;
    if (i < 3 * DIM * DIM) g_wqkv[i] = (bf16)qkv_w[i];
    if (i < DIM * DIM)     g_wproj[i] = (bf16)proj_w[i];
    if (i < NH * NT * NT) {
        int h = i >> 12, qk = i & 4095;
        int q = qk >> 6, kv = qk & 63;
        int idx = ((q >> 3) - (kv >> 3) + 7) * 15 + ((q & 7) - (kv & 7) + 7);
        g_biasF[i] = bias_table[idx * NH + h];
    }
}

__device__ inline bf16x8 load_cvt8(const float* p) {
    float4 f0 = *(const float4*)p;
    float4 f1 = *(const float4*)(p + 4);
    bf16x8 a;
    a[0] = (bf16)f0.x; a[1] = (bf16)f0.y; a[2] = (bf16)f0.z; a[3] = (bf16)f0.w;
    a[4] = (bf16)f1.x; a[5] = (bf16)f1.y; a[6] = (bf16)f1.z; a[7] = (bf16)f1.w;
    return a;
}

// One block per window, 8 waves. Double-buffered staging -> 1 barrier per
// head-pair (8 barriers/block total vs 26 before). Attention (scores, bias,
// softmax) is per-wave and in-register; P goes through a wave-private
// XOR-swizzled LDS tile (conflict-free b128 A-frag reads).
// LDS layout (73,728 B):
//   sq  [2][2][64][40] bf16 @ 0       20,480   [buf][hl][tok][d]
//   sk  [2][2][64][40] bf16 @ 20480   20,480
//   svT [2][2][32][64] bf16 @ 40960   16,384   [buf][hl][d][tok], tok ^= (d&7)<<3
//   sP  [8][16][64]    bf16 @ 57344   16,384   [wave][q][kv],     kv  ^= (q&7)<<3
__global__ __launch_bounds__(TPB, 4) void attn_kernel(
    const float* __restrict__ x,          // [4096, 64, 384]
    const float* __restrict__ qkv_b,      // [1152]
    float* __restrict__ out)              // [4096, 64, 384] pre-proj attn out
{
    __shared__ __align__(16) char smem[73728];
    bf16 (*sq)[2][64][40] = (bf16(*)[2][64][40])smem;
    bf16 (*sk)[2][64][40] = (bf16(*)[2][64][40])(smem + 20480);
    bf16* svT = (bf16*)(smem + 40960);
    bf16* sP  = (bf16*)(smem + 57344);

    const int t    = threadIdx.x;
    const int win  = blockIdx.x;
    const int wave = t >> 6;
    const int lane = t & 63;
    const int quad = lane >> 4;
    const int l15  = lane & 15;
    const int mt   = wave & 3;   // m-tile (QKV GEMM) == q-tile (attention)
    const int grp  = wave >> 2;  // nt-range selector (QKV) == head-in-pair (attention)

    // ---- A-fragments straight from global (no LDS staging, no barriers) ----
    const float* xw = x + (size_t)win * (NT * DIM);
    bf16x8 afrag[12];
    #pragma unroll
    for (int ks = 0; ks < 12; ++ks)
        afrag[ks] = load_cvt8(xw + (mt * 16 + l15) * DIM + ks * 32 + quad * 8);

    const float scale = 0.17677669529663687f;  // 32^-0.5
    float* outw = out + (size_t)win * (NT * DIM);
    bf16* const sPw = sP + wave * 1024;

    #pragma unroll 1
    for (int hp = 0; hp < NH / 2; ++hp) {
        const int buf = hp & 1;

        // ---- QKV GEMM: 48 tile jobs (2 heads x 4 m x 6 n), 6 per wave ----
        #pragma unroll
        for (int jj = 0; jj < 6; ++jj) {
            const int hl  = jj / 3;
            const int nt  = grp * 3 + (jj % 3);  // 0..5
            const int s   = nt >> 1;             // 0=q 1=k 2=v
            const int nhh = (nt & 1) * 16;
            const int h   = hp * 2 + hl;
            const int wrow = s * DIM + h * HD + nhh + l15;
            const bf16* Wp = g_wqkv + (size_t)wrow * DIM + quad * 8;
            // two independent 6-deep chains: shorter dep chains, better pipelining
            bf16x8 b0[6], b1[6];
            #pragma unroll
            for (int i = 0; i < 6; ++i) b0[i] = *(const bf16x8*)(Wp + i * 32);
            #pragma unroll
            for (int i = 0; i < 6; ++i) b1[i] = *(const bf16x8*)(Wp + 192 + i * 32);
            floatx4 acc0 = {0.f, 0.f, 0.f, 0.f}, acc1 = {0.f, 0.f, 0.f, 0.f};
            #pragma unroll
            for (int i = 0; i < 6; ++i) {
                acc0 = __builtin_amdgcn_mfma_f32_16x16x32_bf16(afrag[i],     b0[i], acc0, 0, 0, 0);
                acc1 = __builtin_amdgcn_mfma_f32_16x16x32_bf16(afrag[6 + i], b1[i], acc1, 0, 0, 0);
            }
            const float bv = qkv_b[wrow];
            #pragma unroll
            for (int r = 0; r < 4; ++r) {
                const int m = mt * 16 + quad * 4 + r;
                const float v = acc0[r] + acc1[r] + bv;
                if (s == 0)      sq[buf][hl][m][nhh + l15] = (bf16)(v * scale);
                else if (s == 1) sk[buf][hl][m][nhh + l15] = (bf16)v;
                else {
                    const int row = nhh + l15;   // d-channel 0..31
                    svT[(buf * 2 + hl) * 2048 + row * 64 + (m ^ ((row & 7) << 3))] = (bf16)v;
                }
            }
        }
        __syncthreads();   // the ONLY barrier per head-pair

        // ---- per-wave attention: wave -> (head grp, q-rows mt*16..+16) ----
        const int h = hp * 2 + grp;
        const float* bias = g_biasF + h * (NT * NT) + (mt * 16 + quad * 4) * NT + l15;
        float bb[4][4];
        #pragma unroll
        for (int jt = 0; jt < 4; ++jt)
            #pragma unroll
            for (int r = 0; r < 4; ++r)
                bb[jt][r] = bias[r * NT + jt * 16];

        // scores: S[q=quad*4+r][kv=jt*16+l15], 4 independent MFMAs
        const bf16x8 aq = *(const bf16x8*)&sq[buf][grp][mt * 16 + l15][quad * 8];
        floatx4 sc[4];
        #pragma unroll
        for (int jt = 0; jt < 4; ++jt) {
            const bf16x8 bk = *(const bf16x8*)&sk[buf][grp][jt * 16 + l15][quad * 8];
            floatx4 z = {0.f, 0.f, 0.f, 0.f};
            sc[jt] = __builtin_amdgcn_mfma_f32_16x16x32_bf16(aq, bk, z, 0, 0, 0);
        }
        #pragma unroll
        for (int jt = 0; jt < 4; ++jt)
            #pragma unroll
            for (int r = 0; r < 4; ++r)
                sc[jt][r] += bb[jt][r];

        // softmax in-register: row fixed per (quad,r); cols across l15 lanes x 4 jt.
        // shfl_xor 1/2/4/8 reduces within each 16-lane group (quad bits untouched).
        float mx[4], sm[4], inv[4];
        #pragma unroll
        for (int r = 0; r < 4; ++r) {
            mx[r] = fmaxf(fmaxf(sc[0][r], sc[1][r]), fmaxf(sc[2][r], sc[3][r]));
            mx[r] = fmaxf(mx[r], __shfl_xor(mx[r], 1));
            mx[r] = fmaxf(mx[r], __shfl_xor(mx[r], 2));
            mx[r] = fmaxf(mx[r], __shfl_xor(mx[r], 4));
            mx[r] = fmaxf(mx[r], __shfl_xor(mx[r], 8));
        }
        float e[4][4];
        #pragma unroll
        for (int jt = 0; jt < 4; ++jt)
            #pragma unroll
            for (int r = 0; r < 4; ++r)
                e[jt][r] = __expf(sc[jt][r] - mx[r]);
        #pragma unroll
        for (int r = 0; r < 4; ++r) {
            sm[r] = (e[0][r] + e[1][r]) + (e[2][r] + e[3][r]);
            sm[r] += __shfl_xor(sm[r], 1);
            sm[r] += __shfl_xor(sm[r], 2);
            sm[r] += __shfl_xor(sm[r], 4);
            sm[r] += __shfl_xor(sm[r], 8);
            inv[r] = 1.0f / sm[r];
        }
        // P -> wave-private swizzled LDS tile (transpose for the PV A-operand)
        #pragma unroll
        for (int jt = 0; jt < 4; ++jt)
            #pragma unroll
            for (int r = 0; r < 4; ++r) {
                const int row = quad * 4 + r;
                const int col = jt * 16 + l15;
                sPw[row * 64 + (col ^ ((row & 7) << 3))] = (bf16)(e[jt][r] * inv[r]);
            }

        // ---- PV: out 16x32 per wave, K=64 (2 k-steps x 2 n-tiles) ----
        bf16x8 ap[2];
        #pragma unroll
        for (int ks = 0; ks < 2; ++ks)
            ap[ks] = *(const bf16x8*)&sPw[l15 * 64 + ((ks * 32 + quad * 8) ^ ((l15 & 7) << 3))];
        const bf16* vb = svT + (buf * 2 + grp) * 2048;
        #pragma unroll
        for (int pnt = 0; pnt < 2; ++pnt) {
            floatx4 acc = {0.f, 0.f, 0.f, 0.f};
            #pragma unroll
            for (int ks = 0; ks < 2; ++ks) {
                const int vrow = pnt * 16 + l15;
                const bf16x8 bv = *(const bf16x8*)&vb[vrow * 64 + ((ks * 32 + quad * 8) ^ ((vrow & 7) << 3))];
                acc = __builtin_amdgcn_mfma_f32_16x16x32_bf16(ap[ks], bv, acc, 0, 0, 0);
            }
            #pragma unroll
            for (int r = 0; r < 4; ++r)
                outw[(size_t)(mt * 16 + quad * 4 + r) * DIM + h * HD + pnt * 16 + l15] = acc[r];
        }
        // no trailing barrier: next hp writes the other buffer; the next
        // post-QKV barrier orders reuse of this one.
    }
}

// In-place projection, LDS-free and barrier-free: each wave reads only its own
// 16-row stripe (A-frags straight from global into regs; stores are
// data-dependent on all 12 loads, so in-place is safe within the wave).
__global__ __launch_bounds__(PTPB, 4) void proj_kernel(
    const float* __restrict__ proj_b,
    float* __restrict__ out)
{
    const int t    = threadIdx.x;
    const int wave = t >> 6;
    const int lane = t & 63;
    const int quad = lane >> 4;
    const int l15  = lane & 15;
    float* base = out + (size_t)blockIdx.x * (NT * DIM);

    bf16x8 afrag[12];
    #pragma unroll
    for (int ks = 0; ks < 12; ++ks)
        afrag[ks] = load_cvt8(base + (wave * 16 + l15) * DIM + ks * 32 + quad * 8);

    #pragma unroll
    for (int nt = 0; nt < DIM / 16; ++nt) {
        const bf16* Wp = g_wproj + (size_t)(nt * 16 + l15) * DIM + quad * 8;
        bf16x8 b0[6], b1[6];
        #pragma unroll
        for (int i = 0; i < 6; ++i) b0[i] = *(const bf16x8*)(Wp + i * 32);
        #pragma unroll
        for (int i = 0; i < 6; ++i) b1[i] = *(const bf16x8*)(Wp + 192 + i * 32);
        floatx4 acc0 = {0.f, 0.f, 0.f, 0.f}, acc1 = {0.f, 0.f, 0.f, 0.f};
        #pragma unroll
        for (int i = 0; i < 6; ++i) {
            acc0 = __builtin_amdgcn_mfma_f32_16x16x32_bf16(afrag[i],     b0[i], acc0, 0, 0, 0);
            acc1 = __builtin_amdgcn_mfma_f32_16x16x32_bf16(afrag[6 + i], b1[i], acc1, 0, 0, 0);
        }
        const float pb = proj_b[nt * 16 + l15];
        #pragma unroll
        for (int r = 0; r < 4; ++r)
            base[(size_t)(wave * 16 + quad * 4 + r) * DIM + nt * 16 + l15] = acc0[r] + acc1[r] + pb;
    }
}

extern "C" void kernel_launch(void* const* d_in, const int* in_sizes, int n_in,
                              void* d_out, int out_size, void* d_ws, size_t ws_size,
                              hipStream_t stream) {
    const float* x          = (const float*)d_in[0];
    const float* qkv_w      = (const float*)d_in[1];
    const float* qkv_b      = (const float*)d_in[2];
    const float* proj_w     = (const float*)d_in[3];
    const float* proj_b     = (const float*)d_in[4];
    const float* bias_table = (const float*)d_in[5];
    float* out = (float*)d_out;

    convert_weights<<<dim3((3 * DIM * DIM + 255) / 256), dim3(256), 0, stream>>>(qkv_w, proj_w, bias_table);
    attn_kernel<<<dim3(NWIN), dim3(TPB), 0, stream>>>(x, qkv_b, out);
    proj_kernel<<<dim3(NWIN), dim3(PTPB), 0, stream>>>(proj_b, out);
}